// Round 8
// baseline (95.960 us; speedup 1.0000x reference)
//
#include <hip/hip_runtime.h>

#define N_NODES 50000
#define N_EDGES 800000
#define N_RELS  8
#define NCOL    576          // 9 * 64 output cols (8 relations + self-loop)
#define MAXDEG  64           // avg deg 16 (Poisson); P(deg>64) ~ 1e-20
#define BPACK_ELEMS (NCOL * 64)                          // 36864 bf16

typedef __attribute__((ext_vector_type(8))) short short8;
typedef __attribute__((ext_vector_type(4))) float f32x4;

static __device__ __forceinline__ short f2bf(float f) {
    unsigned u = __float_as_uint(f);
    unsigned r = (u + 0x7FFFu + ((u >> 16) & 1u)) >> 16;   // RNE
    return (short)r;
}
static __device__ __forceinline__ float bf2f(unsigned short b) {
    return __uint_as_float(((unsigned)b) << 16);
}

// ---------------------------------------------------------------------------
// Pre-pack B (8 rels + self-loop) into MFMA fragment order; also zeroes cnt.
// grid = 196 blocks * 256 thr = 50176 >= max(BPACK_ELEMS, N_NODES).
// ---------------------------------------------------------------------------
__global__ __launch_bounds__(256) void k_bpack(const float* __restrict__ W,
                                               const float* __restrict__ lw,
                                               unsigned short* __restrict__ Bpack,
                                               int* __restrict__ cnt) {
    const int id = blockIdx.x * 256 + threadIdx.x;
    if (id < N_NODES) cnt[id] = 0;
    if (id >= BPACK_ELEMS) return;
    const int e    = id & 7;
    const int lane = (id >> 3) & 63;
    const int g    = id >> 9;            // 0..71
    const int w    = g / 18;
    const int r18  = g - w * 18;
    const int t    = r18 >> 1;
    const int s    = r18 & 1;
    const int c0   = w * 144 + t * 16;
    const int rel  = c0 >> 6;
    const int cc   = (c0 & 63) + (lane & 15);
    const int kk   = s * 32 + (lane >> 4) * 8 + e;
    const float* Bp = (rel < 8) ? (W + (size_t)rel * 4096) : lw;
    Bpack[id] = (unsigned short)f2bf(Bp[(size_t)kk * 64 + cc]);
}

// ---------------------------------------------------------------------------
// MERGED kernel: grid = 3125 blocks of 256. Block b does BOTH:
//   (a) MFMA hw-tile b (16 nodes x 576 cols), and
//   (b) slot-fill for edges [b*256, b*256+256).
// Payload store is NON-TEMPORAL: bypasses the private (non-shared) XCD L2 so
// the 8B scattered writes merge in the shared Infinity Cache instead of each
// costing a 64B partial-line eviction (round-7 counters: ~48MB thrash).
// ---------------------------------------------------------------------------
__global__ __launch_bounds__(256) void k_hwfill(const float* __restrict__ h,
                                                const unsigned short* __restrict__ Bpack,
                                                unsigned short* __restrict__ hw2,
                                                const int* __restrict__ src,
                                                const int* __restrict__ dst,
                                                const int* __restrict__ rel,
                                                const float* __restrict__ norm,
                                                int* __restrict__ cnt,
                                                unsigned long long* __restrict__ payload) {
    // ---- fill: issue edge loads + cursor atomic EARLY (latency hides below)
    const int e  = blockIdx.x * 256 + threadIdx.x;
    const int   sv = __builtin_nontemporal_load(src + e);
    const int   dv = __builtin_nontemporal_load(dst + e);
    const int   rv = __builtin_nontemporal_load(rel + e);
    const float nv = __builtin_nontemporal_load(norm + e);
    const int pos = atomicAdd(&cnt[dv], 1) & (MAXDEG - 1);   // & = OOB guard

    // ---- hw tile
    const int lane  = threadIdx.x & 63;
    const int w     = threadIdx.x >> 6;
    const int l15   = lane & 15;
    const int lg    = lane >> 4;           // 0..3
    const int wcol0 = w * 144;
    const int n0    = blockIdx.x * 16;

    // B fragments: 18 coalesced 16B loads
    short8 barr[9][2];
#pragma unroll
    for (int t = 0; t < 9; ++t)
#pragma unroll
        for (int s = 0; s < 2; ++s)
            barr[t][s] = *(const short8*)(Bpack + ((size_t)(w * 18 + t * 2 + s) * 64 + lane) * 8);

    // A fragments: row = l15, k = s*32 + lg*8 + e
    short8 afr[2];
    const float* hp = h + (size_t)(n0 + l15) * 64 + lg * 8;
#pragma unroll
    for (int s = 0; s < 2; ++s) {
        const float4 x = *(const float4*)(hp + s * 32);
        const float4 y = *(const float4*)(hp + s * 32 + 4);
        short8 a;
        a[0] = f2bf(x.x); a[1] = f2bf(x.y); a[2] = f2bf(x.z); a[3] = f2bf(x.w);
        a[4] = f2bf(y.x); a[5] = f2bf(y.y); a[6] = f2bf(y.z); a[7] = f2bf(y.w);
        afr[s] = a;
    }

    f32x4 acc[9];
#pragma unroll
    for (int t = 0; t < 9; ++t) {
        f32x4 c = {0.f, 0.f, 0.f, 0.f};
        c = __builtin_amdgcn_mfma_f32_16x16x32_bf16(afr[0], barr[t][0], c, 0, 0, 0);
        c = __builtin_amdgcn_mfma_f32_16x16x32_bf16(afr[1], barr[t][1], c, 0, 0, 0);
        acc[t] = c;
    }

    // ---- fill: non-temporal scattered payload store (merges in IF$)
    {
        const unsigned long long rec =
            ((unsigned long long)__float_as_uint(nv) << 32) | (unsigned)(sv * 9 + rv);
        __builtin_nontemporal_store(rec, payload + ((size_t)dv * MAXDEG + pos));
    }

    // stage D through swizzled LDS: (row,c) -> u16 idx row*576 + (c ^ (lg<<4))
    __shared__ unsigned short lds[16 * NCOL];   // 18.4 KB
#pragma unroll
    for (int t = 0; t < 9; ++t) {
        const int c = wcol0 + t * 16 + l15;
#pragma unroll
        for (int r = 0; r < 4; ++r) {
            const int row = lg * 4 + r;   // D: col=lane&15, row=lg*4+reg
            lds[row * NCOL + (c ^ (lg << 4))] = (unsigned short)f2bf(acc[t][r]);
        }
    }
    __syncthreads();

    // coalesced copy-out: 16 rows x 288 u32; read applies the same swizzle
    const unsigned* ldsu = (const unsigned*)lds;       // pitch 288 u32
    unsigned* outu = (unsigned*)hw2;
#pragma unroll
    for (int i = threadIdx.x; i < 16 * 288; i += 256) {
        const int row = i / 288;
        const int cu  = i - row * 288;
        outu[(size_t)(n0 + row) * 288 + cu] = ldsu[row * 288 + (cu ^ ((row >> 2) << 3))];
    }
}

// ---------------------------------------------------------------------------
// Gather: one wave per node. 8-wide unroll, int4 payload loads (2 edges/load),
// 4 accumulator chains -> 8 concurrent hw2 gathers in flight.
// ---------------------------------------------------------------------------
__global__ __launch_bounds__(256) void k_gather(const unsigned short* __restrict__ hw2,
                                                const int* __restrict__ cnt,
                                                const int2* __restrict__ payload,
                                                const float* __restrict__ bias,
                                                float* __restrict__ out) {
    const int lane = threadIdx.x & 63;
    const int n = (blockIdx.x * 256 + threadIdx.x) >> 6;
    if (n >= N_NODES) return;
    const int deg = min(cnt[n], MAXDEG);
    const int2* pl  = payload + (size_t)n * MAXDEG;
    const int4* pl4 = (const int4*)pl;                 // 16B-aligned (n*512B)

    float a0 = bias[lane] + bf2f(hw2[(size_t)n * NCOL + 512 + lane]);  // self-loop
    float a1 = 0.f, a2 = 0.f, a3 = 0.f;
    int t = 0;
    for (; t + 8 <= deg; t += 8) {
        const int4 q0 = pl4[(t >> 1) + 0];
        const int4 q1 = pl4[(t >> 1) + 1];
        const int4 q2 = pl4[(t >> 1) + 2];
        const int4 q3 = pl4[(t >> 1) + 3];
        const float v0 = bf2f(hw2[(size_t)q0.x * 64 + lane]);
        const float v1 = bf2f(hw2[(size_t)q0.z * 64 + lane]);
        const float v2 = bf2f(hw2[(size_t)q1.x * 64 + lane]);
        const float v3 = bf2f(hw2[(size_t)q1.z * 64 + lane]);
        const float v4 = bf2f(hw2[(size_t)q2.x * 64 + lane]);
        const float v5 = bf2f(hw2[(size_t)q2.z * 64 + lane]);
        const float v6 = bf2f(hw2[(size_t)q3.x * 64 + lane]);
        const float v7 = bf2f(hw2[(size_t)q3.z * 64 + lane]);
        a0 += v0 * __int_as_float(q0.y);
        a1 += v1 * __int_as_float(q0.w);
        a2 += v2 * __int_as_float(q1.y);
        a3 += v3 * __int_as_float(q1.w);
        a0 += v4 * __int_as_float(q2.y);
        a1 += v5 * __int_as_float(q2.w);
        a2 += v6 * __int_as_float(q3.y);
        a3 += v7 * __int_as_float(q3.w);
    }
    for (; t + 2 <= deg; t += 2) {
        const int4 q = pl4[t >> 1];
        a0 += bf2f(hw2[(size_t)q.x * 64 + lane]) * __int_as_float(q.y);
        a1 += bf2f(hw2[(size_t)q.z * 64 + lane]) * __int_as_float(q.w);
    }
    if (t < deg) {
        const int2 p = pl[t];
        a0 += bf2f(hw2[(size_t)p.x * 64 + lane]) * __int_as_float(p.y);
    }
    out[(size_t)n * 64 + lane] = fmaxf((a0 + a1) + (a2 + a3), 0.f);
}

// ---------------------------------------------------------------------------
// Fallback path (ws too small): per-edge direct matvec + f32 atomics + finish.
// ---------------------------------------------------------------------------
__global__ __launch_bounds__(256) void k_edge_direct(const float* __restrict__ h,
                                                     const float* __restrict__ W,
                                                     const int* __restrict__ src,
                                                     const int* __restrict__ dst,
                                                     const int* __restrict__ rel,
                                                     const float* __restrict__ norm,
                                                     float* __restrict__ agg) {
    const int lane  = threadIdx.x & 63;
    const int warp  = (blockIdx.x * 256 + threadIdx.x) >> 6;
    const int nwarp = (gridDim.x * 256) >> 6;
    for (int e = warp; e < N_EDGES; e += nwarp) {
        const int   s  = src[e];
        const int   d2 = dst[e];
        const int   rr = rel[e];
        const float nm = norm[e];
        const float4* hp = (const float4*)(h + (size_t)s * 64);
        const float*  Wr = W + (size_t)rr * 4096;
        float acc = 0.f;
#pragma unroll
        for (int q = 0; q < 16; ++q) {
            float4 hv = hp[q];
            acc += hv.x * Wr[(4 * q + 0) * 64 + lane];
            acc += hv.y * Wr[(4 * q + 1) * 64 + lane];
            acc += hv.z * Wr[(4 * q + 2) * 64 + lane];
            acc += hv.w * Wr[(4 * q + 3) * 64 + lane];
        }
        atomicAdd(&agg[(size_t)d2 * 64 + lane], acc * nm);
    }
}

__global__ __launch_bounds__(256) void k_final(float* __restrict__ out,
                                               const float* __restrict__ h,
                                               const float* __restrict__ lw,
                                               const float* __restrict__ bias) {
    __shared__ float lws[4096];
    for (int i = threadIdx.x; i < 4096; i += 256) lws[i] = lw[i];
    __syncthreads();
    const int lane  = threadIdx.x & 63;
    const int warp  = (blockIdx.x * 256 + threadIdx.x) >> 6;
    const int nwarp = (gridDim.x * 256) >> 6;
    const float b = bias[lane];
    for (int n = warp; n < N_NODES; n += nwarp) {
        const float4* hp = (const float4*)(h + (size_t)n * 64);
        float acc = b;
#pragma unroll
        for (int q = 0; q < 16; ++q) {
            float4 hv = hp[q];
            acc += hv.x * lws[(4 * q + 0) * 64 + lane];
            acc += hv.y * lws[(4 * q + 1) * 64 + lane];
            acc += hv.z * lws[(4 * q + 2) * 64 + lane];
            acc += hv.w * lws[(4 * q + 3) * 64 + lane];
        }
        const size_t idx = (size_t)n * 64 + lane;
        const float v = out[idx] + acc;
        out[idx] = v > 0.f ? v : 0.f;
    }
}

extern "C" void kernel_launch(void* const* d_in, const int* in_sizes, int n_in,
                              void* d_out, int out_size, void* d_ws, size_t ws_size,
                              hipStream_t stream) {
    const float* h    = (const float*)d_in[0];
    const float* norm = (const float*)d_in[1];
    const float* W    = (const float*)d_in[2];
    const float* lw   = (const float*)d_in[3];
    const float* bias = (const float*)d_in[4];
    const int*   src  = (const int*)d_in[5];
    const int*   dst  = (const int*)d_in[6];
    const int*   rel  = (const int*)d_in[7];
    float* out = (float*)d_out;

    // --- workspace layout -------------------------------------------------
    char* ws = (char*)d_ws;
    unsigned short* hw2 = (unsigned short*)ws;                 // 50000*576 bf16 = 57.6 MB
    int2* payload = (int2*)(ws + (size_t)N_NODES * NCOL * 2);  // 50000*64 int2 = 25.6 MB
    int*  cnt     = (int*)(payload + (size_t)N_NODES * MAXDEG);
    unsigned short* Bpack = (unsigned short*)(cnt + N_NODES + 16);  // 36864 bf16
    const size_t need = (size_t)((char*)(Bpack + BPACK_ELEMS) - ws);

    if (ws_size >= need) {
        k_bpack<<<196, 256, 0, stream>>>(W, lw, Bpack, cnt);
        k_hwfill<<<N_NODES / 16, 256, 0, stream>>>(h, Bpack, hw2, src, dst, rel, norm,
                                                   cnt, (unsigned long long*)payload);
        k_gather<<<(N_NODES + 3) / 4, 256, 0, stream>>>(hw2, cnt, payload, bias, out);
    } else {
        // fallback: atomic scatter path
        hipMemsetAsync(out, 0, (size_t)out_size * sizeof(float), stream);
        k_edge_direct<<<2048, 256, 0, stream>>>(h, W, src, dst, rel, norm, out);
        k_final<<<1024, 256, 0, stream>>>(out, h, lw, bias);
    }
}

// Round 9
// 82.500 us; speedup vs baseline: 1.1631x; 1.1631x over previous
//
#include <hip/hip_runtime.h>

#define N_NODES 50000
#define N_EDGES 800000
#define N_RELS  8
#define NCOL    576          // 9 * 64 output cols (8 relations + self-loop)
#define MAXDEG  64           // avg deg 16 (Poisson); P(deg>64) ~ 1e-20
#define BPACK_ELEMS (NCOL * 64)                          // 36864 bf16

typedef __attribute__((ext_vector_type(8))) short short8;
typedef __attribute__((ext_vector_type(4))) float f32x4;

static __device__ __forceinline__ short f2bf(float f) {
    unsigned u = __float_as_uint(f);
    unsigned r = (u + 0x7FFFu + ((u >> 16) & 1u)) >> 16;   // RNE
    return (short)r;
}
static __device__ __forceinline__ float bf2f(unsigned short b) {
    return __uint_as_float(((unsigned)b) << 16);
}

// ---------------------------------------------------------------------------
// Pre-pack B (8 rels + self-loop) into MFMA fragment order; also zeroes cnt.
// grid = 196 blocks * 256 thr = 50176 >= max(BPACK_ELEMS, N_NODES).
// ---------------------------------------------------------------------------
__global__ __launch_bounds__(256) void k_bpack(const float* __restrict__ W,
                                               const float* __restrict__ lw,
                                               unsigned short* __restrict__ Bpack,
                                               int* __restrict__ cnt) {
    const int id = blockIdx.x * 256 + threadIdx.x;
    if (id < N_NODES) cnt[id] = 0;
    if (id >= BPACK_ELEMS) return;
    const int e    = id & 7;
    const int lane = (id >> 3) & 63;
    const int g    = id >> 9;            // 0..71
    const int w    = g / 18;
    const int r18  = g - w * 18;
    const int t    = r18 >> 1;
    const int s    = r18 & 1;
    const int c0   = w * 144 + t * 16;
    const int rel  = c0 >> 6;
    const int cc   = (c0 & 63) + (lane & 15);
    const int kk   = s * 32 + (lane >> 4) * 8 + e;
    const float* Bp = (rel < 8) ? (W + (size_t)rel * 4096) : lw;
    Bpack[id] = (unsigned short)f2bf(Bp[(size_t)kk * 64 + cc]);
}

// ---------------------------------------------------------------------------
// MERGED kernel: grid = 3125 blocks of 256. Block b does BOTH:
//   (a) MFMA hw-tile b (16 nodes x 576 cols), and
//   (b) slot-fill for edges [b*256, b*256+256).
// Round-9 change vs round-7: payload store moved to the VERY END — after the
// barrier and copy-out — so its random-address ack latency drains at endpgm
// instead of at the pre-barrier s_waitcnt vmcnt(0) where all 4 waves stall.
// (Round-8 NT-store experiment: removed the same stall but evicted payload
// from cache, costing gather +27us. Normal store keeps payload L2/IF$-warm.)
// ---------------------------------------------------------------------------
__global__ __launch_bounds__(256) void k_hwfill(const float* __restrict__ h,
                                                const unsigned short* __restrict__ Bpack,
                                                unsigned short* __restrict__ hw2,
                                                const int* __restrict__ src,
                                                const int* __restrict__ dst,
                                                const int* __restrict__ rel,
                                                const float* __restrict__ norm,
                                                int* __restrict__ cnt,
                                                unsigned long long* __restrict__ payload) {
    // ---- fill: edge loads + cursor atomic issued EARLY (latency hides below)
    const int e  = blockIdx.x * 256 + threadIdx.x;
    const int   sv = src[e];
    const int   dv = dst[e];
    const int   rv = rel[e];
    const float nv = norm[e];
    const int pos = atomicAdd(&cnt[dv], 1) & (MAXDEG - 1);   // & = OOB guard

    // ---- hw tile
    const int lane  = threadIdx.x & 63;
    const int w     = threadIdx.x >> 6;
    const int l15   = lane & 15;
    const int lg    = lane >> 4;           // 0..3
    const int wcol0 = w * 144;
    const int n0    = blockIdx.x * 16;

    // B fragments: 18 coalesced 16B loads
    short8 barr[9][2];
#pragma unroll
    for (int t = 0; t < 9; ++t)
#pragma unroll
        for (int s = 0; s < 2; ++s)
            barr[t][s] = *(const short8*)(Bpack + ((size_t)(w * 18 + t * 2 + s) * 64 + lane) * 8);

    // A fragments: row = l15, k = s*32 + lg*8 + e
    short8 afr[2];
    const float* hp = h + (size_t)(n0 + l15) * 64 + lg * 8;
#pragma unroll
    for (int s = 0; s < 2; ++s) {
        const float4 x = *(const float4*)(hp + s * 32);
        const float4 y = *(const float4*)(hp + s * 32 + 4);
        short8 a;
        a[0] = f2bf(x.x); a[1] = f2bf(x.y); a[2] = f2bf(x.z); a[3] = f2bf(x.w);
        a[4] = f2bf(y.x); a[5] = f2bf(y.y); a[6] = f2bf(y.z); a[7] = f2bf(y.w);
        afr[s] = a;
    }

    f32x4 acc[9];
#pragma unroll
    for (int t = 0; t < 9; ++t) {
        f32x4 c = {0.f, 0.f, 0.f, 0.f};
        c = __builtin_amdgcn_mfma_f32_16x16x32_bf16(afr[0], barr[t][0], c, 0, 0, 0);
        c = __builtin_amdgcn_mfma_f32_16x16x32_bf16(afr[1], barr[t][1], c, 0, 0, 0);
        acc[t] = c;
    }

    // stage D through swizzled LDS: (row,c) -> u16 idx row*576 + (c ^ (lg<<4))
    __shared__ unsigned short lds[16 * NCOL];   // 18.4 KB
#pragma unroll
    for (int t = 0; t < 9; ++t) {
        const int c = wcol0 + t * 16 + l15;
#pragma unroll
        for (int r = 0; r < 4; ++r) {
            const int row = lg * 4 + r;   // D: col=lane&15, row=lg*4+reg
            lds[row * NCOL + (c ^ (lg << 4))] = (unsigned short)f2bf(acc[t][r]);
        }
    }
    __syncthreads();

    // coalesced copy-out: 16 rows x 288 u32; read applies the same swizzle
    const unsigned* ldsu = (const unsigned*)lds;       // pitch 288 u32
    unsigned* outu = (unsigned*)hw2;
#pragma unroll
    for (int i = threadIdx.x; i < 16 * 288; i += 256) {
        const int row = i / 288;
        const int cu  = i - row * 288;
        outu[(size_t)(n0 + row) * 288 + cu] = ldsu[row * 288 + (cu ^ ((row >> 2) << 3))];
    }

    // ---- fill: scattered payload store LAST (drains at endpgm, off the
    // barrier-critical path; normal cached store keeps it warm for gather)
    const unsigned long long rec =
        ((unsigned long long)__float_as_uint(nv) << 32) | (unsigned)(sv * 9 + rv);
    payload[(size_t)dv * MAXDEG + pos] = rec;
}

// ---------------------------------------------------------------------------
// Gather: one wave per node. 8-wide unroll, int4 payload loads (2 edges/load),
// 4 accumulator chains -> 8 concurrent hw2 gathers in flight.
// ---------------------------------------------------------------------------
__global__ __launch_bounds__(256) void k_gather(const unsigned short* __restrict__ hw2,
                                                const int* __restrict__ cnt,
                                                const int2* __restrict__ payload,
                                                const float* __restrict__ bias,
                                                float* __restrict__ out) {
    const int lane = threadIdx.x & 63;
    const int n = (blockIdx.x * 256 + threadIdx.x) >> 6;
    if (n >= N_NODES) return;
    const int deg = min(cnt[n], MAXDEG);
    const int2* pl  = payload + (size_t)n * MAXDEG;
    const int4* pl4 = (const int4*)pl;                 // 16B-aligned (n*512B)

    float a0 = bias[lane] + bf2f(hw2[(size_t)n * NCOL + 512 + lane]);  // self-loop
    float a1 = 0.f, a2 = 0.f, a3 = 0.f;
    int t = 0;
    for (; t + 8 <= deg; t += 8) {
        const int4 q0 = pl4[(t >> 1) + 0];
        const int4 q1 = pl4[(t >> 1) + 1];
        const int4 q2 = pl4[(t >> 1) + 2];
        const int4 q3 = pl4[(t >> 1) + 3];
        const float v0 = bf2f(hw2[(size_t)q0.x * 64 + lane]);
        const float v1 = bf2f(hw2[(size_t)q0.z * 64 + lane]);
        const float v2 = bf2f(hw2[(size_t)q1.x * 64 + lane]);
        const float v3 = bf2f(hw2[(size_t)q1.z * 64 + lane]);
        const float v4 = bf2f(hw2[(size_t)q2.x * 64 + lane]);
        const float v5 = bf2f(hw2[(size_t)q2.z * 64 + lane]);
        const float v6 = bf2f(hw2[(size_t)q3.x * 64 + lane]);
        const float v7 = bf2f(hw2[(size_t)q3.z * 64 + lane]);
        a0 += v0 * __int_as_float(q0.y);
        a1 += v1 * __int_as_float(q0.w);
        a2 += v2 * __int_as_float(q1.y);
        a3 += v3 * __int_as_float(q1.w);
        a0 += v4 * __int_as_float(q2.y);
        a1 += v5 * __int_as_float(q2.w);
        a2 += v6 * __int_as_float(q3.y);
        a3 += v7 * __int_as_float(q3.w);
    }
    for (; t + 2 <= deg; t += 2) {
        const int4 q = pl4[t >> 1];
        a0 += bf2f(hw2[(size_t)q.x * 64 + lane]) * __int_as_float(q.y);
        a1 += bf2f(hw2[(size_t)q.z * 64 + lane]) * __int_as_float(q.w);
    }
    if (t < deg) {
        const int2 p = pl[t];
        a0 += bf2f(hw2[(size_t)p.x * 64 + lane]) * __int_as_float(p.y);
    }
    out[(size_t)n * 64 + lane] = fmaxf((a0 + a1) + (a2 + a3), 0.f);
}

// ---------------------------------------------------------------------------
// Fallback path (ws too small): per-edge direct matvec + f32 atomics + finish.
// ---------------------------------------------------------------------------
__global__ __launch_bounds__(256) void k_edge_direct(const float* __restrict__ h,
                                                     const float* __restrict__ W,
                                                     const int* __restrict__ src,
                                                     const int* __restrict__ dst,
                                                     const int* __restrict__ rel,
                                                     const float* __restrict__ norm,
                                                     float* __restrict__ agg) {
    const int lane  = threadIdx.x & 63;
    const int warp  = (blockIdx.x * 256 + threadIdx.x) >> 6;
    const int nwarp = (gridDim.x * 256) >> 6;
    for (int e = warp; e < N_EDGES; e += nwarp) {
        const int   s  = src[e];
        const int   d2 = dst[e];
        const int   rr = rel[e];
        const float nm = norm[e];
        const float4* hp = (const float4*)(h + (size_t)s * 64);
        const float*  Wr = W + (size_t)rr * 4096;
        float acc = 0.f;
#pragma unroll
        for (int q = 0; q < 16; ++q) {
            float4 hv = hp[q];
            acc += hv.x * Wr[(4 * q + 0) * 64 + lane];
            acc += hv.y * Wr[(4 * q + 1) * 64 + lane];
            acc += hv.z * Wr[(4 * q + 2) * 64 + lane];
            acc += hv.w * Wr[(4 * q + 3) * 64 + lane];
        }
        atomicAdd(&agg[(size_t)d2 * 64 + lane], acc * nm);
    }
}

__global__ __launch_bounds__(256) void k_final(float* __restrict__ out,
                                               const float* __restrict__ h,
                                               const float* __restrict__ lw,
                                               const float* __restrict__ bias) {
    __shared__ float lws[4096];
    for (int i = threadIdx.x; i < 4096; i += 256) lws[i] = lw[i];
    __syncthreads();
    const int lane  = threadIdx.x & 63;
    const int warp  = (blockIdx.x * 256 + threadIdx.x) >> 6;
    const int nwarp = (gridDim.x * 256) >> 6;
    const float b = bias[lane];
    for (int n = warp; n < N_NODES; n += nwarp) {
        const float4* hp = (const float4*)(h + (size_t)n * 64);
        float acc = b;
#pragma unroll
        for (int q = 0; q < 16; ++q) {
            float4 hv = hp[q];
            acc += hv.x * lws[(4 * q + 0) * 64 + lane];
            acc += hv.y * lws[(4 * q + 1) * 64 + lane];
            acc += hv.z * lws[(4 * q + 2) * 64 + lane];
            acc += hv.w * lws[(4 * q + 3) * 64 + lane];
        }
        const size_t idx = (size_t)n * 64 + lane;
        const float v = out[idx] + acc;
        out[idx] = v > 0.f ? v : 0.f;
    }
}

extern "C" void kernel_launch(void* const* d_in, const int* in_sizes, int n_in,
                              void* d_out, int out_size, void* d_ws, size_t ws_size,
                              hipStream_t stream) {
    const float* h    = (const float*)d_in[0];
    const float* norm = (const float*)d_in[1];
    const float* W    = (const float*)d_in[2];
    const float* lw   = (const float*)d_in[3];
    const float* bias = (const float*)d_in[4];
    const int*   src  = (const int*)d_in[5];
    const int*   dst  = (const int*)d_in[6];
    const int*   rel  = (const int*)d_in[7];
    float* out = (float*)d_out;

    // --- workspace layout -------------------------------------------------
    char* ws = (char*)d_ws;
    unsigned short* hw2 = (unsigned short*)ws;                 // 50000*576 bf16 = 57.6 MB
    int2* payload = (int2*)(ws + (size_t)N_NODES * NCOL * 2);  // 50000*64 int2 = 25.6 MB
    int*  cnt     = (int*)(payload + (size_t)N_NODES * MAXDEG);
    unsigned short* Bpack = (unsigned short*)(cnt + N_NODES + 16);  // 36864 bf16
    const size_t need = (size_t)((char*)(Bpack + BPACK_ELEMS) - ws);

    if (ws_size >= need) {
        k_bpack<<<196, 256, 0, stream>>>(W, lw, Bpack, cnt);
        k_hwfill<<<N_NODES / 16, 256, 0, stream>>>(h, Bpack, hw2, src, dst, rel, norm,
                                                   cnt, (unsigned long long*)payload);
        k_gather<<<(N_NODES + 3) / 4, 256, 0, stream>>>(hw2, cnt, payload, bias, out);
    } else {
        // fallback: atomic scatter path
        hipMemsetAsync(out, 0, (size_t)out_size * sizeof(float), stream);
        k_edge_direct<<<2048, 256, 0, stream>>>(h, W, src, dst, rel, norm, out);
        k_final<<<1024, 256, 0, stream>>>(out, h, lw, bias);
    }
}